// Round 1
// baseline (509.946 us; speedup 1.0000x reference)
//
#include <hip/hip_runtime.h>
#include <hip/hip_bf16.h>

typedef __attribute__((ext_vector_type(8))) short short8;   // 8 bf16 (4 VGPRs) — MFMA A/B frag
typedef __attribute__((ext_vector_type(4))) float f32x4;    // MFMA C/D frag

#define D_IN   256
#define D_OUT  256
#define NSAMP  32

// round-to-nearest-even f32 -> bf16
static __device__ __forceinline__ unsigned short f2bf(float f) {
    unsigned int u = __builtin_bit_cast(unsigned int, f);
    u += 0x7fffu + ((u >> 16) & 1u);
    return (unsigned short)(u >> 16);
}

// Convert W [256][256] f32 row-major -> bf16 in MFMA B-fragment order.
// For k-step ks (32 k's) and n-frag nf (16 cols), lane l needs
// B[k = ks*32 + 8*(l>>4) + j][n = nf*16 + (l&15)], j=0..7, as 16 contiguous bytes.
__global__ void wconv_kernel(const float* __restrict__ W,
                             unsigned short* __restrict__ wsw) {
    const int k = blockIdx.x;    // 0..255
    const int n = threadIdx.x;   // 0..255
    const float v = W[k * D_OUT + n];
    const int ks = k >> 5, kg = (k >> 3) & 3, j = k & 7;
    const int nf = n >> 4, c = n & 15;
    const int lane = kg * 16 + c;
    const int dst = ((ks * 16 + nf) * 64 + lane) * 8 + j;
    wsw[dst] = f2bf(v);
}

// Fused: gather+mean -> LDS (bf16, swizzled) -> MFMA GEMM with W -> bias+ReLU+L2norm -> out
__global__ __launch_bounds__(256, 4) void gcn_fused_kernel(
        const int*  __restrict__ node_idx,
        const int*  __restrict__ neigh_idx,
        const float* __restrict__ features,
        const unsigned short* __restrict__ wsw,
        const float* __restrict__ bias,
        float* __restrict__ out,
        int n_nodes)
{
    __shared__ __attribute__((aligned(16))) unsigned char lds[64 * D_IN * 2]; // 32 KB bf16 agg tile

    const int tid  = threadIdx.x;
    const int wv   = tid >> 6;       // wave 0..3
    const int lane = tid & 63;
    const int block_m0 = blockIdx.x * 64;

    // ---------------- Phase 1: gather + mean, 16 nodes per wave ----------------
    const float scale = 1.0f / (float)(NSAMP + 1);
    for (int r = 0; r < 16; ++r) {
        const int row  = wv * 16 + r;
        const int node = block_m0 + row;
        float ax = 0.f, ay = 0.f, az = 0.f, aw = 0.f;
        if (node < n_nodes) {
            // vector-load the 32 neighbor indices (lanes 0..31; 32..63 duplicate)
            const int nb   = neigh_idx[node * NSAMP + (lane & 31)];
            const int self = node_idx[node];
            {
                const float4 v = *(const float4*)(features + (size_t)self * D_IN + lane * 4);
                ax += v.x; ay += v.y; az += v.z; aw += v.w;
            }
            #pragma unroll 8
            for (int s = 0; s < NSAMP; ++s) {
                const int idx = __shfl(nb, s, 64);
                const float4 v = *(const float4*)(features + (size_t)idx * D_IN + lane * 4);
                ax += v.x; ay += v.y; az += v.z; aw += v.w;
            }
            ax *= scale; ay *= scale; az *= scale; aw *= scale;
        }
        // pack 4 bf16 and store to swizzled LDS (row stride 512 B; XOR bits 4-6 by row&7)
        ushort4 pk;
        pk.x = f2bf(ax); pk.y = f2bf(ay); pk.z = f2bf(az); pk.w = f2bf(aw);
        unsigned int bo = (unsigned int)(row * 512 + lane * 8) ^ ((unsigned int)(row & 7) << 4);
        *(ushort4*)(&lds[bo]) = pk;
    }

    __syncthreads();

    // ---------------- Phase 2: GEMM  agg[64x256] @ W[256x256] ----------------
    // A frag (16x16x32 bf16): lane l holds A[row=l&15][k = ks*32 + 8*(l>>4) + j], j=0..7
    f32x4 acc[16];
    #pragma unroll
    for (int i = 0; i < 16; ++i) acc[i] = (f32x4)(0.0f);

    const int arow = wv * 16 + (lane & 15);
    const int acol = (lane >> 4) * 16;   // byte offset of this lane's 8 bf16 within the 64-byte k-step chunk
    const short8* __restrict__ wp = (const short8*)wsw;

    #pragma unroll
    for (int ks = 0; ks < 8; ++ks) {
        unsigned int bo = (unsigned int)(arow * 512 + ks * 64 + acol)
                        ^ ((unsigned int)(arow & 7) << 4);
        const short8 afrag = *(const short8*)(&lds[bo]);
        #pragma unroll
        for (int nf = 0; nf < 16; ++nf) {
            const short8 bfrag = wp[(ks * 16 + nf) * 64 + lane];
            acc[nf] = __builtin_amdgcn_mfma_f32_16x16x32_bf16(afrag, bfrag, acc[nf], 0, 0, 0);
        }
    }

    // ---------------- Phase 3: bias + ReLU + row L2-norm + store ----------------
    // D frag: col = lane&15 (+16*nf), row = wv*16 + 4*(lane>>4) + j
    float p[4] = {0.f, 0.f, 0.f, 0.f};
    #pragma unroll
    for (int nf = 0; nf < 16; ++nf) {
        const float bv = bias[nf * 16 + (lane & 15)];
        #pragma unroll
        for (int j = 0; j < 4; ++j) {
            float v = acc[nf][j] + bv;
            v = fmaxf(v, 0.0f);
            acc[nf][j] = v;
            p[j] += v * v;
        }
    }
    // reduce sum-of-squares across the 16 lanes (l&15) holding one row
    #pragma unroll
    for (int m = 1; m < 16; m <<= 1) {
        p[0] += __shfl_xor(p[0], m, 64);
        p[1] += __shfl_xor(p[1], m, 64);
        p[2] += __shfl_xor(p[2], m, 64);
        p[3] += __shfl_xor(p[3], m, 64);
    }
    float inv[4];
    #pragma unroll
    for (int j = 0; j < 4; ++j)
        inv[j] = 1.0f / fmaxf(sqrtf(p[j]), 1e-12f);

    const int rbase = block_m0 + wv * 16 + (lane >> 4) * 4;
    const int c0 = lane & 15;
    #pragma unroll
    for (int j = 0; j < 4; ++j) {
        const int rg = rbase + j;
        if (rg < n_nodes) {
            #pragma unroll
            for (int nf = 0; nf < 16; ++nf)
                out[(size_t)rg * D_OUT + nf * 16 + c0] = acc[nf][j] * inv[j];
        }
    }
}

extern "C" void kernel_launch(void* const* d_in, const int* in_sizes, int n_in,
                              void* d_out, int out_size, void* d_ws, size_t ws_size,
                              hipStream_t stream) {
    const int*   node_idx  = (const int*)d_in[0];
    const int*   neigh_idx = (const int*)d_in[1];
    const float* features  = (const float*)d_in[2];
    const float* W         = (const float*)d_in[3];
    const float* bias      = (const float*)d_in[4];
    float*       out       = (float*)d_out;
    const int n_nodes = in_sizes[0];

    unsigned short* wsw = (unsigned short*)d_ws;  // 128 KB fragment-order bf16 W

    hipLaunchKernelGGL(wconv_kernel, dim3(D_IN), dim3(D_OUT), 0, stream, W, wsw);

    const int nblocks = (n_nodes + 63) / 64;
    hipLaunchKernelGGL(gcn_fused_kernel, dim3(nblocks), dim3(256), 0, stream,
                       node_idx, neigh_idx, features, wsw, bias, out, n_nodes);
}